// Round 1
// baseline (296.346 us; speedup 1.0000x reference)
//
#include <hip/hip_runtime.h>

typedef unsigned short u16;
typedef float  f32x4  __attribute__((ext_vector_type(4)));
typedef __bf16 bf16x8 __attribute__((ext_vector_type(8)));
typedef u16    u16x2  __attribute__((ext_vector_type(2)));
typedef u16    u16x4  __attribute__((ext_vector_type(4)));

#define D_MODEL 1024
#define D_INNER 2048
#define B_SZ    2
#define SEQ     4096
#define MROWS   (B_SZ * SEQ)       // 8192
#define LTAPS   64                 // FIR truncation; f[tau] ~ 0.4^tau -> 1e-26 at 64
#define KFIR    192                // per-tile K window: s in [t0-64, t0+128)
#define PAD     128                // left zero pad of vT rows
#define SP      (SEQ + PAD)        // 4224, padded row length of vT

__device__ __forceinline__ u16 f2bf(float f) {
    unsigned u = __builtin_bit_cast(unsigned, f);
    unsigned r = u + 0x7FFFu + ((u >> 16) & 1u);
    return (u16)(r >> 16);
}
__device__ __forceinline__ float bf2f(u16 h) {
    unsigned u = ((unsigned)h) << 16;
    return __builtin_bit_cast(float, u);
}

typedef __attribute__((address_space(1))) void gv_t;
typedef __attribute__((address_space(3))) void lv_t;
__device__ __forceinline__ void glds16(const u16* g, u16* l) {
    __builtin_amdgcn_global_load_lds((gv_t*)g, (lv_t*)l, 16, 0, 0);
}

// ---------------------------------------------------------------------------
// Setup: f[tau] = Cp^T tanh(A)^tau Bp  (+Dp at tau=0), then build the shared
// Toeplitz tile Amat[128][192], Amat[i][j] = f[64+i-j] (0 outside [0,64)).
// ---------------------------------------------------------------------------
__global__ __launch_bounds__(256) void setup_kernel(
    const float* __restrict__ A, const float* __restrict__ Bp,
    const float* __restrict__ Cp, const float* __restrict__ Dp,
    u16* __restrict__ Amat)
{
    __shared__ float fs[LTAPS];
    const int tid = threadIdx.x;
    if (tid < 64) {
        const int i = tid & 15;            // lanes replicate in groups of 16
        float Atr[16];
        for (int j = 0; j < 16; j++) Atr[j] = tanhf(A[i * 16 + j]);
        float p = Bp[i];
        const float c  = Cp[i];
        const float d0 = Dp[0];
        for (int t = 0; t < LTAPS; t++) {
            float fv = c * p;
            fv += __shfl_xor(fv, 1); fv += __shfl_xor(fv, 2);
            fv += __shfl_xor(fv, 4); fv += __shfl_xor(fv, 8);
            if (tid == 0) fs[t] = fv + (t == 0 ? d0 : 0.f);
            float np = 0.f;
            for (int j = 0; j < 16; j++) np = fmaf(Atr[j], __shfl(p, j), np);
            p = np;
        }
    }
    __syncthreads();
    for (int idx = tid; idx < 128 * KFIR; idx += 256) {
        int i = idx / KFIR, j = idx % KFIR;
        int tau = 64 + i - j;
        float v = (tau >= 0 && tau < LTAPS) ? fs[tau] : 0.f;
        Amat[idx] = f2bf(v);
    }
}

// ---------------------------------------------------------------------------
// fp32 -> bf16 elementwise (x)
// ---------------------------------------------------------------------------
__global__ __launch_bounds__(256) void cvt_kernel(
    const float* __restrict__ in, u16* __restrict__ out)
{
    size_t i = ((size_t)blockIdx.x * 256 + threadIdx.x) * 4;
    f32x4 v = *(const f32x4*)(in + i);
    u16x4 o;
    o.x = f2bf(v.x); o.y = f2bf(v.y); o.z = f2bf(v.z); o.w = f2bf(v.w);
    *(u16x4*)(out + i) = o;
}

// ---------------------------------------------------------------------------
// fp32 [R][C] -> bf16 [C][R] transpose (weights)
// ---------------------------------------------------------------------------
__global__ __launch_bounds__(256) void transpose_cvt(
    const float* __restrict__ in, u16* __restrict__ out, int R, int C)
{
    __shared__ float tile[32][33];
    const int c0 = blockIdx.x * 32, r0 = blockIdx.y * 32;
    const int tx = threadIdx.x & 31, ty = threadIdx.x >> 5;   // 32 x 8
    for (int k = 0; k < 32; k += 8)
        tile[ty + k][tx] = in[(size_t)(r0 + ty + k) * C + c0 + tx];
    __syncthreads();
    for (int k = 0; k < 32; k += 8)
        out[(size_t)(c0 + ty + k) * R + r0 + tx] = f2bf(tile[tx][ty + k]);
}

// ---------------------------------------------------------------------------
// bt-GEMM, m97 structure: C[m][n] = sum_k A[m][k]*BT[n][k] + bias[n]
// BM=BN=128, BK=32, 256 thr (4 waves, 64x64 quadrant each), 16x16x32 bf16 MFMA
// MODE 0: store bf16; MODE 1: store fp32
// ---------------------------------------------------------------------------
template <int MODE>
__global__ __launch_bounds__(256) void gemm_bt_kernel(
    const u16* __restrict__ A, const u16* __restrict__ BT,
    void* __restrict__ Cout, const float* __restrict__ bias,
    int M, int N, int K)
{
    __shared__ u16 As[128 * 32];
    __shared__ u16 Bs[128 * 32];
    const int tid = threadIdx.x, lane = tid & 63, wid = tid >> 6;
    const int m0 = blockIdx.y * 128, n0 = blockIdx.x * 128;
    // staging: each wave covers 32 rows (2 instrs of 16 rows); lane -> row l/4, kchunk l%4
    const int sr = wid * 32 + (lane >> 2);
    const int sc = (lane & 3) * 8;
    const u16* ga = A  + (size_t)(m0 + sr) * K + sc;
    const u16* gb = BT + (size_t)(n0 + sr) * K + sc;
    u16* la = As + wid * 1024;
    u16* lb = Bs + wid * 1024;
    const int wm = (wid & 1) * 64, wn = (wid >> 1) * 64;
    const int fr = lane & 15, fq = lane >> 4;
    f32x4 acc[4][4] = {};
    for (int k0 = 0; k0 < K; k0 += 32) {
        glds16(ga + k0, la);
        glds16(ga + k0 + (size_t)16 * K, la + 512);
        glds16(gb + k0, lb);
        glds16(gb + k0 + (size_t)16 * K, lb + 512);
        asm volatile("s_waitcnt vmcnt(0)" ::: "memory");
        __syncthreads();
        bf16x8 af[4], bfr[4];
        for (int i = 0; i < 4; i++)
            af[i]  = *(const bf16x8*)(As + (wm + i * 16 + fr) * 32 + fq * 8);
        for (int i = 0; i < 4; i++)
            bfr[i] = *(const bf16x8*)(Bs + (wn + i * 16 + fr) * 32 + fq * 8);
        for (int mi = 0; mi < 4; mi++)
            for (int ni = 0; ni < 4; ni++)
                acc[mi][ni] = __builtin_amdgcn_mfma_f32_16x16x32_bf16(
                    af[mi], bfr[ni], acc[mi][ni], 0, 0, 0);
        __syncthreads();
    }
    for (int ni = 0; ni < 4; ni++) {
        const int col = n0 + wn + ni * 16 + fr;
        const float bv = bias[col];
        for (int mi = 0; mi < 4; mi++) {
            const int rowb = m0 + wm + mi * 16 + fq * 4;
            f32x4 v = acc[mi][ni];
            for (int r = 0; r < 4; r++) {
                float val = v[r] + bv;
                if constexpr (MODE == 0)
                    ((u16*)Cout)[(size_t)(rowb + r) * N + col] = f2bf(val);
                else
                    ((float*)Cout)[(size_t)(rowb + r) * N + col] = val;
            }
        }
    }
}

// ---------------------------------------------------------------------------
// Depthwise causal conv(4) + transpose: u[b][t][c] -> vT[b][c][PAD+t] (bf16)
// zero pad vT[.][0..PAD) so the FIR GEMM needs no boundary branches
// ---------------------------------------------------------------------------
__global__ __launch_bounds__(256) void conv_kernel(
    const u16* __restrict__ u, const float* __restrict__ cw,
    const float* __restrict__ cb, u16* __restrict__ vT)
{
    __shared__ float ut[67][65];
    const int tid = threadIdx.x;
    const int c0 = blockIdx.x * 64, t0 = blockIdx.y * 64, b = blockIdx.z;
    for (int idx = tid; idx < 67 * 32; idx += 256) {
        int r = idx >> 5, cp = (idx & 31) * 2;
        int gt = t0 + r - 3;
        float v0 = 0.f, v1 = 0.f;
        if (gt >= 0) {
            u16x2 d = *(const u16x2*)(u + ((size_t)(b * SEQ + gt)) * D_INNER + c0 + cp);
            v0 = bf2f(d.x); v1 = bf2f(d.y);
        }
        ut[r][cp] = v0; ut[r][cp + 1] = v1;
    }
    __syncthreads();
    const int lane = tid & 63, wrow = tid >> 6;
    for (int k = 0; k < 16; k++) {
        const int c  = wrow + k * 4;           // 0..63, wave-uniform
        const int cg = c0 + c;
        const float w0 = cw[cg * 4 + 0], w1 = cw[cg * 4 + 1];
        const float w2 = cw[cg * 4 + 2], w3 = cw[cg * 4 + 3];
        float v = cb[cg]
                + w0 * ut[lane + 0][c] + w1 * ut[lane + 1][c]
                + w2 * ut[lane + 2][c] + w3 * ut[lane + 3][c];
        u16* row = vT + ((size_t)(b * D_INNER + cg)) * SP;
        row[PAD + t0 + lane] = f2bf(v);
        if (t0 == 0) { row[lane] = 0; row[64 + lane] = 0; }
    }
}

// ---------------------------------------------------------------------------
// FIR as GEMM: Y[t][c] = sum_j Amat[i][j] * vT[c][t0-64+j], then silu -> bf16
// grid: x = c-tiles (16), y = t-tiles (32), z = batch (2)
// ---------------------------------------------------------------------------
__global__ __launch_bounds__(256) void fir_gemm_kernel(
    const u16* __restrict__ Amat, const u16* __restrict__ vT,
    u16* __restrict__ Y)
{
    __shared__ u16 As[128 * 32];
    __shared__ u16 Bs[128 * 32];
    const int tid = threadIdx.x, lane = tid & 63, wid = tid >> 6;
    const int c0 = blockIdx.x * 128, t0 = blockIdx.y * 128, b = blockIdx.z;
    const int sr = wid * 32 + (lane >> 2);
    const int sc = (lane & 3) * 8;
    const u16* ga = Amat + sr * KFIR + sc;                       // same for all blocks
    const u16* gb = vT + ((size_t)(b * D_INNER + c0 + sr)) * SP + (t0 + PAD - 64) + sc;
    u16* la = As + wid * 1024;
    u16* lb = Bs + wid * 1024;
    const int wm = (wid & 1) * 64, wn = (wid >> 1) * 64;
    const int fr = lane & 15, fq = lane >> 4;
    f32x4 acc[4][4] = {};
    for (int k0 = 0; k0 < KFIR; k0 += 32) {
        glds16(ga + k0, la);
        glds16(ga + k0 + 16 * KFIR, la + 512);
        glds16(gb + k0, lb);
        glds16(gb + k0 + (size_t)16 * SP, lb + 512);
        asm volatile("s_waitcnt vmcnt(0)" ::: "memory");
        __syncthreads();
        bf16x8 af[4], bfr[4];
        for (int i = 0; i < 4; i++)
            af[i]  = *(const bf16x8*)(As + (wm + i * 16 + fr) * 32 + fq * 8);
        for (int i = 0; i < 4; i++)
            bfr[i] = *(const bf16x8*)(Bs + (wn + i * 16 + fr) * 32 + fq * 8);
        for (int mi = 0; mi < 4; mi++)
            for (int ni = 0; ni < 4; ni++)
                acc[mi][ni] = __builtin_amdgcn_mfma_f32_16x16x32_bf16(
                    af[mi], bfr[ni], acc[mi][ni], 0, 0, 0);
        __syncthreads();
    }
    for (int ni = 0; ni < 4; ni++) {
        const int col = c0 + wn + ni * 16 + fr;
        for (int mi = 0; mi < 4; mi++) {
            const int rowb = t0 + wm + mi * 16 + fq * 4;
            f32x4 v = acc[mi][ni];
            for (int r = 0; r < 4; r++) {
                float y = v[r];
                float s = y / (1.f + __expf(-y));              // silu
                Y[((size_t)(b * SEQ + rowb + r)) * D_INNER + col] = f2bf(s);
            }
        }
    }
}

// ---------------------------------------------------------------------------
extern "C" void kernel_launch(void* const* d_in, const int* in_sizes, int n_in,
                              void* d_out, int out_size, void* d_ws, size_t ws_size,
                              hipStream_t stream)
{
    const float* x    = (const float*)d_in[0];
    const float* Win  = (const float*)d_in[1];
    const float* bin  = (const float*)d_in[2];
    const float* cw   = (const float*)d_in[3];
    const float* cb   = (const float*)d_in[4];
    const float* A    = (const float*)d_in[5];
    const float* Bp   = (const float*)d_in[6];
    const float* Cp   = (const float*)d_in[7];
    const float* Dp   = (const float*)d_in[8];
    const float* Wout = (const float*)d_in[9];
    const float* bout = (const float*)d_in[10];
    float* out = (float*)d_out;

    char* ws = (char*)d_ws;
    u16* xb    = (u16*)(ws);                        // 8192x1024 bf16   16.0 MB
    u16* WinT  = (u16*)(ws + 16777216);             // 2048x1024 bf16    4.0 MB
    u16* WoutT = (u16*)(ws + 20971520);             // 1024x2048 bf16    4.0 MB
    u16* u     = (u16*)(ws + 25165824);             // 8192x2048 bf16   32.0 MB
    u16* vT    = (u16*)(ws + 58720256);             // 2x2048x4224 bf16 33.0 MB
    u16* Amat  = (u16*)(ws + 93323264);             // 128x192 bf16     48 KB
    u16* Ysilu = u;                                 // alias: u dead after conv

    setup_kernel<<<1, 256, 0, stream>>>(A, Bp, Cp, Dp, Amat);
    cvt_kernel<<<8192, 256, 0, stream>>>(x, xb);
    transpose_cvt<<<dim3(64, 32), 256, 0, stream>>>(Win,  WinT,  1024, 2048);
    transpose_cvt<<<dim3(32, 64), 256, 0, stream>>>(Wout, WoutT, 2048, 1024);
    // u = x @ W_in + b_in  (bf16 out)
    gemm_bt_kernel<0><<<dim3(16, 64), 256, 0, stream>>>(xb, WinT, u, bin,
                                                        MROWS, D_INNER, D_MODEL);
    // depthwise conv + transpose -> vT
    conv_kernel<<<dim3(32, 64, 2), 256, 0, stream>>>(u, cw, cb, vT);
    // SSM as truncated-impulse-response Toeplitz GEMM + silu -> Ysilu
    fir_gemm_kernel<<<dim3(16, 32, 2), 256, 0, stream>>>(Amat, vT, Ysilu);
    // out = Ysilu @ W_out + b_out  (fp32 out)
    gemm_bt_kernel<1><<<dim3(8, 64), 256, 0, stream>>>(Ysilu, WoutT, out, bout,
                                                       MROWS, D_MODEL, D_INNER);
}